// Round 19
// baseline (579.539 us; speedup 1.0000x reference)
//
#include <hip/hip_runtime.h>
#include <hip/hip_bf16.h>

typedef short bh8 __attribute__((ext_vector_type(8)));
typedef float fx4 __attribute__((ext_vector_type(4)));
typedef int ivec4 __attribute__((ext_vector_type(4)));

typedef __hip_bfloat16 bf16;

__device__ __forceinline__ float bf2f(bf16 v) { return __bfloat162float(v); }
__device__ __forceinline__ bf16 f2bf(float v) { return __float2bfloat16(v); }
__device__ __forceinline__ float bits2f(short s) {
    return __uint_as_float(((unsigned)(unsigned short)s) << 16);
}

#define BB 8
#define SS 1569
#define CC 768
#define R_T 12544   // B*HW*T
#define R_S 12608   // B*T*197
#define R_H 12552   // B*S

__device__ __forceinline__ void gload16(const void* g, void* l) {
    __builtin_amdgcn_global_load_lds(
        (const __attribute__((address_space(1))) void*)g,
        (__attribute__((address_space(3))) void*)l, 16, 0, 0);
}

// swizzled LDS fragment read: element (row, slot) of a [*][64]bf16 tile (128B rows)
// -- zero-conflict layout (measured SQ_LDS_BANK_CONFLICT = 0)
__device__ __forceinline__ bh8 ldsw(const bf16* base, int row, int slot) {
    const char* p = (const char*)base;
    int byte = row * 128 + (((slot ^ row) & 7) << 4);
    return *(const bh8*)(p + byte);
}

// bijective XCD-chunked block swizzle (m204)
__device__ __forceinline__ int xcd_swz(int o, int nwg) {
    int q = nwg >> 3, r = nwg & 7;
    int xcd = o & 7, idx = o >> 3;
    int base = (xcd < r) ? xcd * (q + 1) : r * (q + 1) + (xcd - r) * q;
    return base + idx;
}

// ---------------- one 32x32 transpose tile (fp32 -> bf16) ----------------
__device__ __forceinline__ void tr_tile(const float* __restrict__ in, bf16* __restrict__ out,
                                        int R, int C, int bx, int by, int t)
{
    __shared__ float sm[32][33];
    int c0 = bx * 32, r0 = by * 32;
#pragma unroll
    for (int i = 0; i < 4; i++) {
        int e = t + i * 256;
        int r = e >> 5, c = e & 31;
        sm[r][c] = in[(size_t)(r0 + r) * C + (c0 + c)];
    }
    __syncthreads();
#pragma unroll
    for (int i = 0; i < 4; i++) {
        int e = t + i * 256;
        int r = e >> 5, c = e & 31;
        out[(size_t)(c0 + r) * R + (r0 + c)] = f2bf(sm[c][r]);
    }
}

// All weight transposes + tproj cast in one launch.
__global__ __launch_bounds__(256) void k_transpose_all(
    const float* s0, bf16* d0,   // t_qkv   768x2304
    const float* s1, bf16* d1,   // t_dense 768x768
    const float* s2, bf16* d2,   // s_qkv   768x2304
    const float* s3, bf16* d3,   // s_proj  768x768
    const float* s4, bf16* d4,   // fc1     768x3072
    const float* s5, bf16* d5,   // fc2     3072x768
    const float* s6, bf16* d6)   // cast t_proj 768x768
{
    int b = blockIdx.x, t = threadIdx.x;
    if (b < 1728)      tr_tile(s0, d0, 768, 2304, b % 72, b / 72, t);
    else if (b < 2304) { int x = b - 1728; tr_tile(s1, d1, 768, 768, x % 24, x / 24, t); }
    else if (b < 4032) { int x = b - 2304; tr_tile(s2, d2, 768, 2304, x % 72, x / 72, t); }
    else if (b < 4608) { int x = b - 4032; tr_tile(s3, d3, 768, 768, x % 24, x / 24, t); }
    else if (b < 6912) { int x = b - 4608; tr_tile(s4, d4, 768, 3072, x % 96, x / 96, t); }
    else if (b < 9216) { int x = b - 6912; tr_tile(s5, d5, 3072, 768, x % 24, x / 24, t); }
    else {
        int x = b - 9216;
        size_t base = (size_t)x * 1024 + t * 4;
#pragma unroll
        for (int i = 0; i < 4; i++) d6[base + i] = f2bf(s6[base + i]);
    }
}

// bc[n] = sum_j bp[j]*Wd[j][n] + bd[n]  -- one block per n
__global__ __launch_bounds__(256) void k_bias_comb(
    const float* __restrict__ bp, const bf16* __restrict__ wtd,
    const float* __restrict__ bd, float* __restrict__ bc)
{
    int n = blockIdx.x;
    int tid = threadIdx.x, lane = tid & 63, wave = tid >> 6;
    float acc = 0.f;
    for (int j = tid; j < 768; j += 256) acc += bp[j] * bf2f(wtd[(size_t)n * 768 + j]);
#pragma unroll
    for (int off = 32; off >= 1; off >>= 1) acc += __shfl_xor(acc, off);
    __shared__ float red[4];
    if (lane == 0) red[wave] = acc;
    __syncthreads();
    if (tid == 0) bc[n] = red[0] + red[1] + red[2] + red[3] + bd[n];
}

// ---------------- LayerNorm C=768 (modes 0/1), fp32 in -> bf16 out ----------------
__global__ __launch_bounds__(256) void k_layernorm(
    const float* __restrict__ srcA, const float* __restrict__ srcB,
    const float* __restrict__ gamma, const float* __restrict__ beta,
    bf16* __restrict__ out, int mode)
{
    int r = blockIdx.x;
    const float* row;
    if (mode == 0) {
        int b = r / 1568, rl = r - b * 1568;
        row = srcB + (size_t)(b * SS + 1 + rl) * CC;
    } else {
        int seq = r / 197, pos = r - seq * 197;
        int b = seq >> 3, t = seq & 7;
        if (pos == 0) row = srcB + (size_t)(b * SS) * CC;
        else          row = srcA + (size_t)(b * 1568 + (pos - 1) * 8 + t) * CC;
    }
    int tid = threadIdx.x, lane = tid & 63, wave = tid >> 6;
    float x[3], s = 0.f, ss = 0.f;
#pragma unroll
    for (int i = 0; i < 3; i++) {
        float v = row[tid + i * 256];
        x[i] = v; s += v; ss += v * v;
    }
#pragma unroll
    for (int off = 32; off >= 1; off >>= 1) {
        s  += __shfl_xor(s, off);
        ss += __shfl_xor(ss, off);
    }
    __shared__ float red[2][4];
    if (lane == 0) { red[0][wave] = s; red[1][wave] = ss; }
    __syncthreads();
    float S   = red[0][0] + red[0][1] + red[0][2] + red[0][3];
    float SSQ = red[1][0] + red[1][1] + red[1][2] + red[1][3];
    float mean = S * (1.f / 768.f);
    float var = SSQ * (1.f / 768.f) - mean * mean;
    float inv = rsqrtf(var + 1e-6f);
#pragma unroll
    for (int i = 0; i < 3; i++) {
        int c = tid + i * 256;
        out[(size_t)r * CC + c] = f2bf((x[i] - mean) * inv * gamma[c] + beta[c]);
    }
}

// ---------------- fused hs-assemble + LN2: writes HS (fp32) and X (bf16 LN) ----------------
__global__ __launch_bounds__(256) void k_ln2_fused(
    const float* __restrict__ hidden, const float* __restrict__ temb,
    const bf16*  __restrict__ sout,
    const float* __restrict__ gamma, const float* __restrict__ beta,
    float* __restrict__ hs, bf16* __restrict__ out)
{
    int r = blockIdx.x;
    int b = r / SS, s = r - b * SS;
    int tid = threadIdx.x, lane = tid & 63, wave = tid >> 6;
    float x[3], sm = 0.f, sq = 0.f;
    if (s == 0) {
#pragma unroll
        for (int i = 0; i < 3; i++) {
            int c = tid + i * 256;
            float m = 0.f;
#pragma unroll
            for (int t = 0; t < 8; t++)
                m += bf2f(sout[((size_t)(b * 8 + t) * 197) * CC + c]);
            x[i] = hidden[(size_t)r * CC + c] + m * 0.125f;
        }
    } else {
        int sl = s - 1; int hw = sl >> 3, t = sl & 7;
        const float* trow = temb + (size_t)(b * 1568 + sl) * CC;
        const bf16* srow = sout + (((size_t)(b * 8 + t)) * 197 + 1 + hw) * CC;
#pragma unroll
        for (int i = 0; i < 3; i++) {
            int c = tid + i * 256;
            x[i] = trow[c] + bf2f(srow[c]);
        }
    }
#pragma unroll
    for (int i = 0; i < 3; i++) {
        hs[(size_t)r * CC + tid + i * 256] = x[i];
        sm += x[i]; sq += x[i] * x[i];
    }
#pragma unroll
    for (int off = 32; off >= 1; off >>= 1) {
        sm += __shfl_xor(sm, off);
        sq += __shfl_xor(sq, off);
    }
    __shared__ float red[2][4];
    if (lane == 0) { red[0][wave] = sm; red[1][wave] = sq; }
    __syncthreads();
    float S   = red[0][0] + red[0][1] + red[0][2] + red[0][3];
    float SSQ = red[1][0] + red[1][1] + red[1][2] + red[1][3];
    float mean = S * (1.f / 768.f);
    float var = SSQ * (1.f / 768.f) - mean * mean;
    float inv = rsqrtf(var + 1e-6f);
#pragma unroll
    for (int i = 0; i < 3; i++) {
        int c = tid + i * 256;
        out[(size_t)r * CC + c] = f2bf((x[i] - mean) * inv * gamma[c] + beta[c]);
    }
}

// ---------------- out pre-fill: out = HS + fc2_bias (fp32, float4) ----------------
__global__ __launch_bounds__(256) void k_prefill(
    const float* __restrict__ hs, const float* __restrict__ bias,
    float* __restrict__ out)
{
    size_t i = ((size_t)blockIdx.x * 256 + threadIdx.x) * 4;
    int col = (int)(i % CC);
    float4 h = *(const float4*)(hs + i);
    float4 b = *(const float4*)(bias + col);
    float4 o;
    o.x = h.x + b.x; o.y = h.y + b.y; o.z = h.z + b.z; o.w = h.w + b.w;
    *(float4*)(out + i) = o;
}

// ---------------- 128x128 GEMM, BK=64, 8 waves x (64x32), zero-conflict LDS ------------
// (round-16 kernel, best measured: fc1 100.8us, conflicts 0)
__global__ __launch_bounds__(512, 8) void k_gemm(
    const bf16* __restrict__ A, const bf16* __restrict__ BT,
    const float* __restrict__ bias, bf16* __restrict__ outb, float* __restrict__ outf,
    int M, int N, int K, int mode, const float* __restrict__ resf)
{
    __shared__ __align__(16) bf16 Asm[128 * 64];
    __shared__ __align__(16) bf16 Bsm[128 * 64];
    int tid = threadIdx.x, lane = tid & 63, wave = tid >> 6;
    int nx = N >> 7;
    int f = xcd_swz(blockIdx.x, gridDim.x);
    int m0 = (f / nx) * 128, n0 = (f % nx) * 128;
    int wr = (wave >> 2) * 64, wc = (wave & 3) * 32;
    int c = lane & 15, gr = lane >> 4;
    fx4 acc[4][2];
#pragma unroll
    for (int i = 0; i < 4; i++)
#pragma unroll
        for (int j = 0; j < 2; j++)
            acc[i][j] = fx4{0.f, 0.f, 0.f, 0.f};

    int rlo = lane >> 3;
    int kblk = (lane & 7) ^ rlo;
    const bf16* aG = A  + (size_t)(m0 + wave * 8 + rlo) * K + kblk * 8;
    const bf16* bG = BT + (size_t)(n0 + wave * 8 + rlo) * K + kblk * 8;
    bf16* aL0 = Asm + (wave * 8) * 64;
    bf16* aL1 = Asm + (64 + wave * 8) * 64;
    bf16* bL0 = Bsm + (wave * 8) * 64;
    bf16* bL1 = Bsm + (64 + wave * 8) * 64;

    for (int k0 = 0; k0 < K; k0 += 64) {
        __syncthreads();
        gload16(aG, aL0);
        gload16(aG + (size_t)64 * K, aL1);
        gload16(bG, bL0);
        gload16(bG + (size_t)64 * K, bL1);
        aG += 64; bG += 64;
        __syncthreads();
#pragma unroll
        for (int kk = 0; kk < 2; kk++) {
            bh8 af[4], bfr[2];
#pragma unroll
            for (int i = 0; i < 4; i++)
                af[i] = ldsw(Asm, wr + i * 16 + c, kk * 4 + gr);
#pragma unroll
            for (int nf = 0; nf < 2; nf++)
                bfr[nf] = ldsw(Bsm, wc + nf * 16 + c, kk * 4 + gr);
#pragma unroll
            for (int mi = 0; mi < 4; mi++)
#pragma unroll
                for (int ni = 0; ni < 2; ni++)
                    acc[mi][ni] = __builtin_amdgcn_mfma_f32_16x16x32_bf16(af[mi], bfr[ni], acc[mi][ni], 0, 0, 0);
        }
    }

#pragma unroll
    for (int mi = 0; mi < 4; mi++) {
#pragma unroll
        for (int ni = 0; ni < 2; ni++) {
            int col = n0 + wc + ni * 16 + c;
            float bv = bias ? bias[col] : 0.f;
#pragma unroll
            for (int j = 0; j < 4; j++) {
                int row = m0 + wr + mi * 16 + gr * 4 + j;
                if (row < M) {
                    float v = acc[mi][ni][j] + bv;
                    if (mode == 2) {
                        v = 0.5f * v * (1.f + erff(v * 0.70710678118f));
                        outb[(size_t)row * N + col] = f2bf(v);
                    } else if (mode == 1) {
                        int b = row / 1568, rl = row - b * 1568;
                        v += resf[(size_t)(b * SS + 1 + rl) * CC + col];
                        outf[(size_t)row * N + col] = v;
                    } else if (mode == 3) {
                        v += resf[(size_t)row * CC + col];
                        outf[(size_t)row * N + col] = v;
                    } else {
                        outb[(size_t)row * N + col] = f2bf(v);
                    }
                }
            }
        }
    }
}

// ---------------- split-K GEMM (fc2): partial over Kl, atomicAdd into fp32 out ---------
// Same body/layout as k_gemm; grid = NS * (M/128 ceil)*(N/128); out pre-filled with
// HS + bias by k_prefill. Each block accumulates its K-half and atomically adds.
__global__ __launch_bounds__(512, 8) void k_gemm_sk(
    const bf16* __restrict__ A, const bf16* __restrict__ BT,
    float* __restrict__ outf, int M, int N, int Ks, int Kl)
{
    __shared__ __align__(16) bf16 Asm[128 * 64];
    __shared__ __align__(16) bf16 Bsm[128 * 64];
    int tid = threadIdx.x, lane = tid & 63, wave = tid >> 6;
    int nx = N >> 7;
    int per = ((M + 127) >> 7) * nx;
    int f = xcd_swz(blockIdx.x, gridDim.x);
    int split = f / per;
    int r = f - split * per;
    int m0 = (r / nx) * 128, n0 = (r % nx) * 128;
    int koff = split * Kl;
    int wr = (wave >> 2) * 64, wc = (wave & 3) * 32;
    int c = lane & 15, gr = lane >> 4;
    fx4 acc[4][2];
#pragma unroll
    for (int i = 0; i < 4; i++)
#pragma unroll
        for (int j = 0; j < 2; j++)
            acc[i][j] = fx4{0.f, 0.f, 0.f, 0.f};

    int rlo = lane >> 3;
    int kblk = (lane & 7) ^ rlo;
    const bf16* aG = A  + (size_t)(m0 + wave * 8 + rlo) * Ks + koff + kblk * 8;
    const bf16* bG = BT + (size_t)(n0 + wave * 8 + rlo) * Ks + koff + kblk * 8;
    bf16* aL0 = Asm + (wave * 8) * 64;
    bf16* aL1 = Asm + (64 + wave * 8) * 64;
    bf16* bL0 = Bsm + (wave * 8) * 64;
    bf16* bL1 = Bsm + (64 + wave * 8) * 64;

    for (int k0 = 0; k0 < Kl; k0 += 64) {
        __syncthreads();
        gload16(aG, aL0);
        gload16(aG + (size_t)64 * Ks, aL1);
        gload16(bG, bL0);
        gload16(bG + (size_t)64 * Ks, bL1);
        aG += 64; bG += 64;
        __syncthreads();
#pragma unroll
        for (int kk = 0; kk < 2; kk++) {
            bh8 af[4], bfr[2];
#pragma unroll
            for (int i = 0; i < 4; i++)
                af[i] = ldsw(Asm, wr + i * 16 + c, kk * 4 + gr);
#pragma unroll
            for (int nf = 0; nf < 2; nf++)
                bfr[nf] = ldsw(Bsm, wc + nf * 16 + c, kk * 4 + gr);
#pragma unroll
            for (int mi = 0; mi < 4; mi++)
#pragma unroll
                for (int ni = 0; ni < 2; ni++)
                    acc[mi][ni] = __builtin_amdgcn_mfma_f32_16x16x32_bf16(af[mi], bfr[ni], acc[mi][ni], 0, 0, 0);
        }
    }

#pragma unroll
    for (int mi = 0; mi < 4; mi++) {
#pragma unroll
        for (int ni = 0; ni < 2; ni++) {
            int col = n0 + wc + ni * 16 + c;
#pragma unroll
            for (int j = 0; j < 4; j++) {
                int row = m0 + wr + mi * 16 + gr * 4 + j;
                if (row < M)
                    atomicAdd(&outf[(size_t)row * N + col], acc[mi][ni][j]);
            }
        }
    }
}

// ---------------- temporal attention: 1568 seqs, len 8, 12 heads (vectorized) ----------
__global__ __launch_bounds__(256) void k_temporal_attn(
    const bf16* __restrict__ qkv, bf16* __restrict__ ctx)
{
    int seq = blockIdx.x;
    int tid = threadIdx.x, lane = tid & 63, wave = tid >> 6;
    __shared__ float psm[4][8][8];
    const size_t base = (size_t)seq * 8 * 2304;
    for (int h = wave; h < 12; h += 4) {
        int qi = lane >> 3, kj = lane & 7;
        const bf16* qrow = qkv + base + (size_t)qi * 2304 + h * 64;
        const bf16* krow = qkv + base + (size_t)kj * 2304 + 768 + h * 64;
        float sc = 0.f;
#pragma unroll
        for (int d8 = 0; d8 < 8; d8++) {
            bh8 qv = *(const bh8*)(qrow + d8 * 8);
            bh8 kv = *(const bh8*)(krow + d8 * 8);
#pragma unroll
            for (int e = 0; e < 8; e++)
                sc += bits2f(qv[e]) * bits2f(kv[e]);
        }
        sc *= 0.125f;
        float mx = sc;
#pragma unroll
        for (int off = 1; off < 8; off <<= 1) mx = fmaxf(mx, __shfl_xor(mx, off));
        float p = expf(sc - mx);
        float sum = p;
#pragma unroll
        for (int off = 1; off < 8; off <<= 1) sum += __shfl_xor(sum, off);
        p /= sum;
        psm[wave][qi][kj] = p;
        __syncthreads();
        int dq = lane >> 3, dc = (lane & 7) * 8;
        float pv[8];
#pragma unroll
        for (int k2 = 0; k2 < 8; k2++) pv[k2] = psm[wave][dq][k2];
        float a[8];
#pragma unroll
        for (int e = 0; e < 8; e++) a[e] = 0.f;
#pragma unroll
        for (int k2 = 0; k2 < 8; k2++) {
            bh8 vv = *(const bh8*)(qkv + base + (size_t)k2 * 2304 + 1536 + h * 64 + dc);
            float p2 = pv[k2];
#pragma unroll
            for (int e = 0; e < 8; e++) a[e] += p2 * bits2f(vv[e]);
        }
        bh8 ov;
#pragma unroll
        for (int e = 0; e < 8; e++) {
            bf16 b = f2bf(a[e]);
            ov[e] = *(short*)&b;
        }
        *(bh8*)(ctx + ((size_t)seq * 8 + dq) * CC + h * 64 + dc) = ov;
        __syncthreads();
    }
}

// ---------------- spatial attention (MFMA): one block per (seq, head) ----------------
#define SA_K_BYTES  25216
#define SA_VT_BYTES 28672
#define SA_P_BYTES  7168
__global__ __launch_bounds__(256) void k_spatial_attn(
    const bf16* __restrict__ qkv, bf16* __restrict__ ctx)
{
    __shared__ __align__(16) char smem[SA_K_BYTES + SA_VT_BYTES + 4 * SA_P_BYTES];
    int head = blockIdx.x;
    int seq  = blockIdx.y;
    int tid = threadIdx.x, lane = tid & 63, wave = tid >> 6;
    const size_t base = (size_t)seq * 197 * 2304;
    char* Kb  = smem;
    char* VTb = smem + SA_K_BYTES;
    char* Pb  = smem + SA_K_BYTES + SA_VT_BYTES + wave * SA_P_BYTES;

    for (int idx = tid; idx < 197 * 8; idx += 256) {
        int row = idx >> 3, d8 = idx & 7;
        ivec4 v = *(const ivec4*)(qkv + base + (size_t)row * 2304 + 768 + head * 64 + d8 * 8);
        int byte = row * 128 + d8 * 16;
        *(ivec4*)(Kb + (byte ^ ((row & 7) << 4))) = v;
    }
    // V -> VT staging: coalesced row-major bh8 reads, transpose via LDS scatter writes
    for (int it = tid; it < 224 * 8; it += 256) {
        int r = it >> 3, d8 = (it & 7) * 8;
        bh8 vv = {0, 0, 0, 0, 0, 0, 0, 0};
        if (r < 197) vv = *(const bh8*)(qkv + base + (size_t)r * 2304 + 1536 + head * 64 + d8);
#pragma unroll
        for (int e = 0; e < 8; e++) {
            int d = d8 + e;
            int byte = d * 448 + r * 2;
            *(short*)(VTb + (byte ^ ((d & 7) << 4))) = vv[e];
        }
    }
    for (int idx = lane; idx < 256; idx += 64) {
        int row = idx >> 4, col = 208 + (idx & 15);
        int byte = row * 448 + col * 2;
        *(bf16*)(Pb + (byte ^ ((row & 7) << 4))) = f2bf(0.f);
    }
    __syncthreads();

    int c = lane & 15, g = lane >> 4;
    for (int qt = wave; qt < 13; qt += 4) {
        int qrow = qt * 16 + c;
        int qr = qrow < 197 ? qrow : 196;
        const bf16* qp = qkv + base + (size_t)qr * 2304 + head * 64 + g * 8;
        bh8 qf0 = *(const bh8*)qp;
        bh8 qf1 = *(const bh8*)(qp + 32);

        fx4 s[13];
#pragma unroll
        for (int nt = 0; nt < 13; nt++) s[nt] = fx4{0.f, 0.f, 0.f, 0.f};
#pragma unroll
        for (int nt = 0; nt < 13; nt++) {
            int n = nt * 16 + c;
            int kbyte = n * 128 + g * 16;
            int swz = (n & 7) << 4;
            bh8 b0 = *(const bh8*)(Kb + ((kbyte) ^ swz));
            bh8 b1 = *(const bh8*)(Kb + ((kbyte + 64) ^ swz));
            s[nt] = __builtin_amdgcn_mfma_f32_16x16x32_bf16(qf0, b0, s[nt], 0, 0, 0);
            s[nt] = __builtin_amdgcn_mfma_f32_16x16x32_bf16(qf1, b1, s[nt], 0, 0, 0);
        }
#pragma unroll
        for (int nt = 0; nt < 13; nt++)
#pragma unroll
            for (int j = 0; j < 4; j++) s[nt][j] *= 0.125f;
        if (c >= 5) {
#pragma unroll
            for (int j = 0; j < 4; j++) s[12][j] = -1e30f;
        }
#pragma unroll
        for (int j = 0; j < 4; j++) {
            float mx = s[0][j];
#pragma unroll
            for (int nt = 1; nt < 13; nt++) mx = fmaxf(mx, s[nt][j]);
#pragma unroll
            for (int off = 1; off < 16; off <<= 1) mx = fmaxf(mx, __shfl_xor(mx, off));
            float sum = 0.f;
#pragma unroll
            for (int nt = 0; nt < 13; nt++) {
                float p = __expf(s[nt][j] - mx);
                s[nt][j] = p; sum += p;
            }
#pragma unroll
            for (int off = 1; off < 16; off <<= 1) sum += __shfl_xor(sum, off);
            float inv = 1.f / sum;
#pragma unroll
            for (int nt = 0; nt < 13; nt++) s[nt][j] *= inv;
        }
#pragma unroll
        for (int nt = 0; nt < 13; nt++)
#pragma unroll
            for (int j = 0; j < 4; j++) {
                int row = g * 4 + j, col = nt * 16 + c;
                int byte = row * 448 + col * 2;
                *(bf16*)(Pb + (byte ^ ((row & 7) << 4))) = f2bf(s[nt][j]);
            }
        fx4 o[4];
#pragma unroll
        for (int dt = 0; dt < 4; dt++) o[dt] = fx4{0.f, 0.f, 0.f, 0.f};
#pragma unroll
        for (int kk = 0; kk < 7; kk++) {
            int abyte = c * 448 + kk * 64 + g * 16;
            bh8 pa = *(const bh8*)(Pb + (abyte ^ ((c & 7) << 4)));
#pragma unroll
            for (int dt = 0; dt < 4; dt++) {
                int d = dt * 16 + c;
                int vbyte = d * 448 + kk * 64 + g * 16;
                bh8 vb = *(const bh8*)(VTb + (vbyte ^ ((d & 7) << 4)));
                o[dt] = __builtin_amdgcn_mfma_f32_16x16x32_bf16(pa, vb, o[dt], 0, 0, 0);
            }
        }
#pragma unroll
        for (int j = 0; j < 4; j++) {
            int qrow_o = qt * 16 + g * 4 + j;
            if (qrow_o < 197) {
                bf16* op = ctx + ((size_t)(seq * 197 + qrow_o)) * CC + head * 64 + c;
#pragma unroll
                for (int dt = 0; dt < 4; dt++) op[dt * 16] = f2bf(o[dt][j]);
            }
        }
    }
}

extern "C" void kernel_launch(void* const* d_in, const int* in_sizes, int n_in,
                              void* d_out, int out_size, void* d_ws, size_t ws_size,
                              hipStream_t stream)
{
    (void)in_sizes; (void)n_in; (void)out_size; (void)ws_size;
    const float* hidden    = (const float*)d_in[0];
    const float* ln_t_g    = (const float*)d_in[1];
    const float* ln_t_b    = (const float*)d_in[2];
    const float* t_qkv_w   = (const float*)d_in[3];
    const float* t_qkv_b   = (const float*)d_in[4];
    const float* t_proj_w  = (const float*)d_in[5];
    const float* t_proj_b  = (const float*)d_in[6];
    const float* t_dense_w = (const float*)d_in[7];
    const float* t_dense_b = (const float*)d_in[8];
    const float* ln1_g     = (const float*)d_in[9];
    const float* ln1_b     = (const float*)d_in[10];
    const float* s_qkv_w   = (const float*)d_in[11];
    const float* s_qkv_b   = (const float*)d_in[12];
    const float* s_proj_w  = (const float*)d_in[13];
    const float* s_proj_b  = (const float*)d_in[14];
    const float* ln2_g     = (const float*)d_in[15];
    const float* ln2_b     = (const float*)d_in[16];
    const float* fc1_w     = (const float*)d_in[17];
    const float* fc1_b     = (const float*)d_in[18];
    const float* fc2_w     = (const float*)d_in[19];
    const float* fc2_b     = (const float*)d_in[20];

    char* ws = (char*)d_ws;
    size_t off = 0;
    auto alloc = [&](size_t bytes) -> char* {
        char* p = ws + off; off += (bytes + 255) & ~(size_t)255; return p;
    };
    bf16* wt_tqkv   = (bf16*)alloc((size_t)2304 * 768 * 2);
    bf16* wt_tdense = (bf16*)alloc((size_t)768 * 768 * 2);
    bf16* wt_sqkv   = (bf16*)alloc((size_t)2304 * 768 * 2);
    bf16* wt_sproj  = (bf16*)alloc((size_t)768 * 768 * 2);
    bf16* wt_fc1    = (bf16*)alloc((size_t)3072 * 768 * 2);
    bf16* wt_fc2    = (bf16*)alloc((size_t)768 * 3072 * 2);
    bf16* wcast     = (bf16*)alloc((size_t)768 * 768 * 2);
    bf16* wt_comb   = (bf16*)alloc((size_t)768 * 768 * 2);
    float* bc       = (float*)alloc((size_t)768 * 4);
    bf16* X         = (bf16*)alloc((size_t)R_S * CC * 2);
    char* qkv_base  = alloc((size_t)R_S * 2304 * 2);
    bf16* CTX       = (bf16*)alloc((size_t)R_S * CC * 2);
    bf16* P         = (bf16*)alloc((size_t)R_S * CC * 2);
    float* TEMB     = (float*)alloc((size_t)R_T * CC * 4);
    float* HS       = (float*)alloc((size_t)R_H * CC * 4);
    bf16* QKV = (bf16*)qkv_base;
    bf16* MID = (bf16*)qkv_base;   // MLP intermediate overlaps dead QKV+CTX region

    dim3 blk(256);
    dim3 blk512(512);

    // ---- weight prep ----
    k_transpose_all<<<9792, blk, 0, stream>>>(
        t_qkv_w, wt_tqkv, t_dense_w, wt_tdense, s_qkv_w, wt_sqkv,
        s_proj_w, wt_sproj, fc1_w, wt_fc1, fc2_w, wt_fc2, t_proj_w, wcast);
    k_bias_comb<<<768, blk, 0, stream>>>(t_proj_b, wt_tdense, t_dense_b, bc);
    k_gemm<<<6 * 6, blk512, 0, stream>>>(wt_tdense, wcast, nullptr, wt_comb, nullptr,
                                         768, 768, 768, 0, nullptr);

    // ---- temporal branch ----
    k_layernorm<<<R_T, blk, 0, stream>>>(nullptr, hidden, ln_t_g, ln_t_b, X, 0);
    k_gemm<<<98 * 18, blk512, 0, stream>>>(X, wt_tqkv, t_qkv_b, QKV, nullptr,
                                           R_T, 2304, 768, 0, nullptr);
    k_temporal_attn<<<1568, blk, 0, stream>>>(QKV, CTX);
    k_gemm<<<98 * 6, blk512, 0, stream>>>(CTX, wt_comb, bc, nullptr, TEMB,
                                          R_T, 768, 768, 1, hidden);

    // ---- spatial branch ----
    k_layernorm<<<R_S, blk, 0, stream>>>(TEMB, hidden, ln1_g, ln1_b, X, 1);
    k_gemm<<<99 * 18, blk512, 0, stream>>>(X, wt_sqkv, s_qkv_b, QKV, nullptr,
                                           R_S, 2304, 768, 0, nullptr);
    k_spatial_attn<<<dim3(12, 64), blk, 0, stream>>>(QKV, CTX);
    k_gemm<<<99 * 6, blk512, 0, stream>>>(CTX, wt_sproj, s_proj_b, P, nullptr,
                                          R_S, 768, 768, 0, nullptr);

    // ---- fused hs assembly + LN2 ----
    k_ln2_fused<<<R_H, blk, 0, stream>>>(hidden, TEMB, P, ln2_g, ln2_b, HS, X);

    // ---- MLP ----
    k_gemm<<<99 * 24, blk512, 0, stream>>>(X, wt_fc1, fc1_b, MID, nullptr,
                                           R_H, 3072, 768, 2, nullptr);
    // fc2: pre-fill out = HS + bias, then split-K=2 atomic accumulate
    k_prefill<<<(R_H * CC) / 1024, blk, 0, stream>>>(HS, fc2_b, (float*)d_out);
    k_gemm_sk<<<2 * 99 * 6, blk512, 0, stream>>>(MID, wt_fc2, (float*)d_out,
                                                 R_H, 768, 3072, 1536);
}

// Round 20
// 553.443 us; speedup vs baseline: 1.0472x; 1.0472x over previous
//
#include <hip/hip_runtime.h>
#include <hip/hip_bf16.h>

typedef short bh8 __attribute__((ext_vector_type(8)));
typedef float fx4 __attribute__((ext_vector_type(4)));
typedef int ivec4 __attribute__((ext_vector_type(4)));

typedef __hip_bfloat16 bf16;

__device__ __forceinline__ float bf2f(bf16 v) { return __bfloat162float(v); }
__device__ __forceinline__ bf16 f2bf(float v) { return __float2bfloat16(v); }
__device__ __forceinline__ float bits2f(short s) {
    return __uint_as_float(((unsigned)(unsigned short)s) << 16);
}

#define BB 8
#define SS 1569
#define CC 768
#define R_T 12544   // B*HW*T
#define R_S 12608   // B*T*197
#define R_H 12552   // B*S

__device__ __forceinline__ void gload16(const void* g, void* l) {
    __builtin_amdgcn_global_load_lds(
        (const __attribute__((address_space(1))) void*)g,
        (__attribute__((address_space(3))) void*)l, 16, 0, 0);
}

// swizzled LDS fragment read: element (row, slot) of a [*][64]bf16 tile (128B rows)
// -- zero-conflict layout (measured SQ_LDS_BANK_CONFLICT = 0)
__device__ __forceinline__ bh8 ldsw(const bf16* base, int row, int slot) {
    const char* p = (const char*)base;
    int byte = row * 128 + (((slot ^ row) & 7) << 4);
    return *(const bh8*)(p + byte);
}

// bijective XCD-chunked block swizzle (m204)
__device__ __forceinline__ int xcd_swz(int o, int nwg) {
    int q = nwg >> 3, r = nwg & 7;
    int xcd = o & 7, idx = o >> 3;
    int base = (xcd < r) ? xcd * (q + 1) : r * (q + 1) + (xcd - r) * q;
    return base + idx;
}

// ---------------- one 32x32 transpose tile (fp32 -> bf16) ----------------
__device__ __forceinline__ void tr_tile(const float* __restrict__ in, bf16* __restrict__ out,
                                        int R, int C, int bx, int by, int t)
{
    __shared__ float sm[32][33];
    int c0 = bx * 32, r0 = by * 32;
#pragma unroll
    for (int i = 0; i < 4; i++) {
        int e = t + i * 256;
        int r = e >> 5, c = e & 31;
        sm[r][c] = in[(size_t)(r0 + r) * C + (c0 + c)];
    }
    __syncthreads();
#pragma unroll
    for (int i = 0; i < 4; i++) {
        int e = t + i * 256;
        int r = e >> 5, c = e & 31;
        out[(size_t)(c0 + r) * R + (r0 + c)] = f2bf(sm[c][r]);
    }
}

// All weight transposes + tproj cast in one launch.
__global__ __launch_bounds__(256) void k_transpose_all(
    const float* s0, bf16* d0,   // t_qkv   768x2304
    const float* s1, bf16* d1,   // t_dense 768x768
    const float* s2, bf16* d2,   // s_qkv   768x2304
    const float* s3, bf16* d3,   // s_proj  768x768
    const float* s4, bf16* d4,   // fc1     768x3072
    const float* s5, bf16* d5,   // fc2     3072x768
    const float* s6, bf16* d6)   // cast t_proj 768x768
{
    int b = blockIdx.x, t = threadIdx.x;
    if (b < 1728)      tr_tile(s0, d0, 768, 2304, b % 72, b / 72, t);
    else if (b < 2304) { int x = b - 1728; tr_tile(s1, d1, 768, 768, x % 24, x / 24, t); }
    else if (b < 4032) { int x = b - 2304; tr_tile(s2, d2, 768, 2304, x % 72, x / 72, t); }
    else if (b < 4608) { int x = b - 4032; tr_tile(s3, d3, 768, 768, x % 24, x / 24, t); }
    else if (b < 6912) { int x = b - 4608; tr_tile(s4, d4, 768, 3072, x % 96, x / 96, t); }
    else if (b < 9216) { int x = b - 6912; tr_tile(s5, d5, 3072, 768, x % 24, x / 24, t); }
    else {
        int x = b - 9216;
        size_t base = (size_t)x * 1024 + t * 4;
#pragma unroll
        for (int i = 0; i < 4; i++) d6[base + i] = f2bf(s6[base + i]);
    }
}

// bc[n] = sum_j bp[j]*Wd[j][n] + bd[n]  -- one block per n
__global__ __launch_bounds__(256) void k_bias_comb(
    const float* __restrict__ bp, const bf16* __restrict__ wtd,
    const float* __restrict__ bd, float* __restrict__ bc)
{
    int n = blockIdx.x;
    int tid = threadIdx.x, lane = tid & 63, wave = tid >> 6;
    float acc = 0.f;
    for (int j = tid; j < 768; j += 256) acc += bp[j] * bf2f(wtd[(size_t)n * 768 + j]);
#pragma unroll
    for (int off = 32; off >= 1; off >>= 1) acc += __shfl_xor(acc, off);
    __shared__ float red[4];
    if (lane == 0) red[wave] = acc;
    __syncthreads();
    if (tid == 0) bc[n] = red[0] + red[1] + red[2] + red[3] + bd[n];
}

// ---------------- LayerNorm C=768 (modes 0/1), fp32 in -> bf16 out ----------------
__global__ __launch_bounds__(256) void k_layernorm(
    const float* __restrict__ srcA, const float* __restrict__ srcB,
    const float* __restrict__ gamma, const float* __restrict__ beta,
    bf16* __restrict__ out, int mode)
{
    int r = blockIdx.x;
    const float* row;
    if (mode == 0) {
        int b = r / 1568, rl = r - b * 1568;
        row = srcB + (size_t)(b * SS + 1 + rl) * CC;
    } else {
        int seq = r / 197, pos = r - seq * 197;
        int b = seq >> 3, t = seq & 7;
        if (pos == 0) row = srcB + (size_t)(b * SS) * CC;
        else          row = srcA + (size_t)(b * 1568 + (pos - 1) * 8 + t) * CC;
    }
    int tid = threadIdx.x, lane = tid & 63, wave = tid >> 6;
    float x[3], s = 0.f, ss = 0.f;
#pragma unroll
    for (int i = 0; i < 3; i++) {
        float v = row[tid + i * 256];
        x[i] = v; s += v; ss += v * v;
    }
#pragma unroll
    for (int off = 32; off >= 1; off >>= 1) {
        s  += __shfl_xor(s, off);
        ss += __shfl_xor(ss, off);
    }
    __shared__ float red[2][4];
    if (lane == 0) { red[0][wave] = s; red[1][wave] = ss; }
    __syncthreads();
    float S   = red[0][0] + red[0][1] + red[0][2] + red[0][3];
    float SSQ = red[1][0] + red[1][1] + red[1][2] + red[1][3];
    float mean = S * (1.f / 768.f);
    float var = SSQ * (1.f / 768.f) - mean * mean;
    float inv = rsqrtf(var + 1e-6f);
#pragma unroll
    for (int i = 0; i < 3; i++) {
        int c = tid + i * 256;
        out[(size_t)r * CC + c] = f2bf((x[i] - mean) * inv * gamma[c] + beta[c]);
    }
}

// ---------------- fused hs-assemble + LN2: writes HS (fp32) and X (bf16 LN) ----------------
__global__ __launch_bounds__(256) void k_ln2_fused(
    const float* __restrict__ hidden, const float* __restrict__ temb,
    const bf16*  __restrict__ sout,
    const float* __restrict__ gamma, const float* __restrict__ beta,
    float* __restrict__ hs, bf16* __restrict__ out)
{
    int r = blockIdx.x;
    int b = r / SS, s = r - b * SS;
    int tid = threadIdx.x, lane = tid & 63, wave = tid >> 6;
    float x[3], sm = 0.f, sq = 0.f;
    if (s == 0) {
#pragma unroll
        for (int i = 0; i < 3; i++) {
            int c = tid + i * 256;
            float m = 0.f;
#pragma unroll
            for (int t = 0; t < 8; t++)
                m += bf2f(sout[((size_t)(b * 8 + t) * 197) * CC + c]);
            x[i] = hidden[(size_t)r * CC + c] + m * 0.125f;
        }
    } else {
        int sl = s - 1; int hw = sl >> 3, t = sl & 7;
        const float* trow = temb + (size_t)(b * 1568 + sl) * CC;
        const bf16* srow = sout + (((size_t)(b * 8 + t)) * 197 + 1 + hw) * CC;
#pragma unroll
        for (int i = 0; i < 3; i++) {
            int c = tid + i * 256;
            x[i] = trow[c] + bf2f(srow[c]);
        }
    }
#pragma unroll
    for (int i = 0; i < 3; i++) {
        hs[(size_t)r * CC + tid + i * 256] = x[i];
        sm += x[i]; sq += x[i] * x[i];
    }
#pragma unroll
    for (int off = 32; off >= 1; off >>= 1) {
        sm += __shfl_xor(sm, off);
        sq += __shfl_xor(sq, off);
    }
    __shared__ float red[2][4];
    if (lane == 0) { red[0][wave] = sm; red[1][wave] = sq; }
    __syncthreads();
    float S   = red[0][0] + red[0][1] + red[0][2] + red[0][3];
    float SSQ = red[1][0] + red[1][1] + red[1][2] + red[1][3];
    float mean = S * (1.f / 768.f);
    float var = SSQ * (1.f / 768.f) - mean * mean;
    float inv = rsqrtf(var + 1e-6f);
#pragma unroll
    for (int i = 0; i < 3; i++) {
        int c = tid + i * 256;
        out[(size_t)r * CC + c] = f2bf((x[i] - mean) * inv * gamma[c] + beta[c]);
    }
}

// ---------------- 128x128 GEMM, BK=64, 8 waves x (64x32), zero-conflict LDS ------------
// Best measured configuration (round 18): used for ALL GEMMs.
__global__ __launch_bounds__(512, 8) void k_gemm(
    const bf16* __restrict__ A, const bf16* __restrict__ BT,
    const float* __restrict__ bias, bf16* __restrict__ outb, float* __restrict__ outf,
    int M, int N, int K, int mode, const float* __restrict__ resf)
{
    __shared__ __align__(16) bf16 Asm[128 * 64];
    __shared__ __align__(16) bf16 Bsm[128 * 64];
    int tid = threadIdx.x, lane = tid & 63, wave = tid >> 6;
    int nx = N >> 7;
    int f = xcd_swz(blockIdx.x, gridDim.x);
    int m0 = (f / nx) * 128, n0 = (f % nx) * 128;
    int wr = (wave >> 2) * 64, wc = (wave & 3) * 32;
    int c = lane & 15, gr = lane >> 4;
    fx4 acc[4][2];
#pragma unroll
    for (int i = 0; i < 4; i++)
#pragma unroll
        for (int j = 0; j < 2; j++)
            acc[i][j] = fx4{0.f, 0.f, 0.f, 0.f};

    int rlo = lane >> 3;
    int kblk = (lane & 7) ^ rlo;
    const bf16* aG = A  + (size_t)(m0 + wave * 8 + rlo) * K + kblk * 8;
    const bf16* bG = BT + (size_t)(n0 + wave * 8 + rlo) * K + kblk * 8;
    bf16* aL0 = Asm + (wave * 8) * 64;
    bf16* aL1 = Asm + (64 + wave * 8) * 64;
    bf16* bL0 = Bsm + (wave * 8) * 64;
    bf16* bL1 = Bsm + (64 + wave * 8) * 64;

    for (int k0 = 0; k0 < K; k0 += 64) {
        __syncthreads();
        gload16(aG, aL0);
        gload16(aG + (size_t)64 * K, aL1);
        gload16(bG, bL0);
        gload16(bG + (size_t)64 * K, bL1);
        aG += 64; bG += 64;
        __syncthreads();
#pragma unroll
        for (int kk = 0; kk < 2; kk++) {
            bh8 af[4], bfr[2];
#pragma unroll
            for (int i = 0; i < 4; i++)
                af[i] = ldsw(Asm, wr + i * 16 + c, kk * 4 + gr);
#pragma unroll
            for (int nf = 0; nf < 2; nf++)
                bfr[nf] = ldsw(Bsm, wc + nf * 16 + c, kk * 4 + gr);
#pragma unroll
            for (int mi = 0; mi < 4; mi++)
#pragma unroll
                for (int ni = 0; ni < 2; ni++)
                    acc[mi][ni] = __builtin_amdgcn_mfma_f32_16x16x32_bf16(af[mi], bfr[ni], acc[mi][ni], 0, 0, 0);
        }
    }

#pragma unroll
    for (int mi = 0; mi < 4; mi++) {
#pragma unroll
        for (int ni = 0; ni < 2; ni++) {
            int col = n0 + wc + ni * 16 + c;
            float bv = bias ? bias[col] : 0.f;
#pragma unroll
            for (int j = 0; j < 4; j++) {
                int row = m0 + wr + mi * 16 + gr * 4 + j;
                if (row < M) {
                    float v = acc[mi][ni][j] + bv;
                    if (mode == 2) {
                        v = 0.5f * v * (1.f + erff(v * 0.70710678118f));
                        outb[(size_t)row * N + col] = f2bf(v);
                    } else if (mode == 1) {
                        int b = row / 1568, rl = row - b * 1568;
                        v += resf[(size_t)(b * SS + 1 + rl) * CC + col];
                        outf[(size_t)row * N + col] = v;
                    } else if (mode == 3) {
                        v += resf[(size_t)row * CC + col];
                        outf[(size_t)row * N + col] = v;
                    } else {
                        outb[(size_t)row * N + col] = f2bf(v);
                    }
                }
            }
        }
    }
}

// ---------------- temporal attention: 1568 seqs, len 8, 12 heads (vectorized) ----------
__global__ __launch_bounds__(256) void k_temporal_attn(
    const bf16* __restrict__ qkv, bf16* __restrict__ ctx)
{
    int seq = blockIdx.x;
    int tid = threadIdx.x, lane = tid & 63, wave = tid >> 6;
    __shared__ float psm[4][8][8];
    const size_t base = (size_t)seq * 8 * 2304;
    for (int h = wave; h < 12; h += 4) {
        int qi = lane >> 3, kj = lane & 7;
        const bf16* qrow = qkv + base + (size_t)qi * 2304 + h * 64;
        const bf16* krow = qkv + base + (size_t)kj * 2304 + 768 + h * 64;
        float sc = 0.f;
#pragma unroll
        for (int d8 = 0; d8 < 8; d8++) {
            bh8 qv = *(const bh8*)(qrow + d8 * 8);
            bh8 kv = *(const bh8*)(krow + d8 * 8);
#pragma unroll
            for (int e = 0; e < 8; e++)
                sc += bits2f(qv[e]) * bits2f(kv[e]);
        }
        sc *= 0.125f;
        float mx = sc;
#pragma unroll
        for (int off = 1; off < 8; off <<= 1) mx = fmaxf(mx, __shfl_xor(mx, off));
        float p = expf(sc - mx);
        float sum = p;
#pragma unroll
        for (int off = 1; off < 8; off <<= 1) sum += __shfl_xor(sum, off);
        p /= sum;
        psm[wave][qi][kj] = p;
        __syncthreads();
        int dq = lane >> 3, dc = (lane & 7) * 8;
        float pv[8];
#pragma unroll
        for (int k2 = 0; k2 < 8; k2++) pv[k2] = psm[wave][dq][k2];
        float a[8];
#pragma unroll
        for (int e = 0; e < 8; e++) a[e] = 0.f;
#pragma unroll
        for (int k2 = 0; k2 < 8; k2++) {
            bh8 vv = *(const bh8*)(qkv + base + (size_t)k2 * 2304 + 1536 + h * 64 + dc);
            float p2 = pv[k2];
#pragma unroll
            for (int e = 0; e < 8; e++) a[e] += p2 * bits2f(vv[e]);
        }
        bh8 ov;
#pragma unroll
        for (int e = 0; e < 8; e++) {
            bf16 b = f2bf(a[e]);
            ov[e] = *(short*)&b;
        }
        *(bh8*)(ctx + ((size_t)seq * 8 + dq) * CC + h * 64 + dc) = ov;
        __syncthreads();
    }
}

// ---------------- spatial attention (MFMA): one block per (seq, head) ----------------
#define SA_K_BYTES  25216
#define SA_VT_BYTES 28672
#define SA_P_BYTES  7168
__global__ __launch_bounds__(256) void k_spatial_attn(
    const bf16* __restrict__ qkv, bf16* __restrict__ ctx)
{
    __shared__ __align__(16) char smem[SA_K_BYTES + SA_VT_BYTES + 4 * SA_P_BYTES];
    int head = blockIdx.x;
    int seq  = blockIdx.y;
    int tid = threadIdx.x, lane = tid & 63, wave = tid >> 6;
    const size_t base = (size_t)seq * 197 * 2304;
    char* Kb  = smem;
    char* VTb = smem + SA_K_BYTES;
    char* Pb  = smem + SA_K_BYTES + SA_VT_BYTES + wave * SA_P_BYTES;

    for (int idx = tid; idx < 197 * 8; idx += 256) {
        int row = idx >> 3, d8 = idx & 7;
        ivec4 v = *(const ivec4*)(qkv + base + (size_t)row * 2304 + 768 + head * 64 + d8 * 8);
        int byte = row * 128 + d8 * 16;
        *(ivec4*)(Kb + (byte ^ ((row & 7) << 4))) = v;
    }
    // V -> VT staging: coalesced row-major bh8 reads, transpose via LDS scatter writes
    for (int it = tid; it < 224 * 8; it += 256) {
        int r = it >> 3, d8 = (it & 7) * 8;
        bh8 vv = {0, 0, 0, 0, 0, 0, 0, 0};
        if (r < 197) vv = *(const bh8*)(qkv + base + (size_t)r * 2304 + 1536 + head * 64 + d8);
#pragma unroll
        for (int e = 0; e < 8; e++) {
            int d = d8 + e;
            int byte = d * 448 + r * 2;
            *(short*)(VTb + (byte ^ ((d & 7) << 4))) = vv[e];
        }
    }
    for (int idx = lane; idx < 256; idx += 64) {
        int row = idx >> 4, col = 208 + (idx & 15);
        int byte = row * 448 + col * 2;
        *(bf16*)(Pb + (byte ^ ((row & 7) << 4))) = f2bf(0.f);
    }
    __syncthreads();

    int c = lane & 15, g = lane >> 4;
    for (int qt = wave; qt < 13; qt += 4) {
        int qrow = qt * 16 + c;
        int qr = qrow < 197 ? qrow : 196;
        const bf16* qp = qkv + base + (size_t)qr * 2304 + head * 64 + g * 8;
        bh8 qf0 = *(const bh8*)qp;
        bh8 qf1 = *(const bh8*)(qp + 32);

        fx4 s[13];
#pragma unroll
        for (int nt = 0; nt < 13; nt++) s[nt] = fx4{0.f, 0.f, 0.f, 0.f};
#pragma unroll
        for (int nt = 0; nt < 13; nt++) {
            int n = nt * 16 + c;
            int kbyte = n * 128 + g * 16;
            int swz = (n & 7) << 4;
            bh8 b0 = *(const bh8*)(Kb + ((kbyte) ^ swz));
            bh8 b1 = *(const bh8*)(Kb + ((kbyte + 64) ^ swz));
            s[nt] = __builtin_amdgcn_mfma_f32_16x16x32_bf16(qf0, b0, s[nt], 0, 0, 0);
            s[nt] = __builtin_amdgcn_mfma_f32_16x16x32_bf16(qf1, b1, s[nt], 0, 0, 0);
        }
#pragma unroll
        for (int nt = 0; nt < 13; nt++)
#pragma unroll
            for (int j = 0; j < 4; j++) s[nt][j] *= 0.125f;
        if (c >= 5) {
#pragma unroll
            for (int j = 0; j < 4; j++) s[12][j] = -1e30f;
        }
#pragma unroll
        for (int j = 0; j < 4; j++) {
            float mx = s[0][j];
#pragma unroll
            for (int nt = 1; nt < 13; nt++) mx = fmaxf(mx, s[nt][j]);
#pragma unroll
            for (int off = 1; off < 16; off <<= 1) mx = fmaxf(mx, __shfl_xor(mx, off));
            float sum = 0.f;
#pragma unroll
            for (int nt = 0; nt < 13; nt++) {
                float p = __expf(s[nt][j] - mx);
                s[nt][j] = p; sum += p;
            }
#pragma unroll
            for (int off = 1; off < 16; off <<= 1) sum += __shfl_xor(sum, off);
            float inv = 1.f / sum;
#pragma unroll
            for (int nt = 0; nt < 13; nt++) s[nt][j] *= inv;
        }
#pragma unroll
        for (int nt = 0; nt < 13; nt++)
#pragma unroll
            for (int j = 0; j < 4; j++) {
                int row = g * 4 + j, col = nt * 16 + c;
                int byte = row * 448 + col * 2;
                *(bf16*)(Pb + (byte ^ ((row & 7) << 4))) = f2bf(s[nt][j]);
            }
        fx4 o[4];
#pragma unroll
        for (int dt = 0; dt < 4; dt++) o[dt] = fx4{0.f, 0.f, 0.f, 0.f};
#pragma unroll
        for (int kk = 0; kk < 7; kk++) {
            int abyte = c * 448 + kk * 64 + g * 16;
            bh8 pa = *(const bh8*)(Pb + (abyte ^ ((c & 7) << 4)));
#pragma unroll
            for (int dt = 0; dt < 4; dt++) {
                int d = dt * 16 + c;
                int vbyte = d * 448 + kk * 64 + g * 16;
                bh8 vb = *(const bh8*)(VTb + (vbyte ^ ((d & 7) << 4)));
                o[dt] = __builtin_amdgcn_mfma_f32_16x16x32_bf16(pa, vb, o[dt], 0, 0, 0);
            }
        }
#pragma unroll
        for (int j = 0; j < 4; j++) {
            int qrow_o = qt * 16 + g * 4 + j;
            if (qrow_o < 197) {
                bf16* op = ctx + ((size_t)(seq * 197 + qrow_o)) * CC + head * 64 + c;
#pragma unroll
                for (int dt = 0; dt < 4; dt++) op[dt * 16] = f2bf(o[dt][j]);
            }
        }
    }
}

extern "C" void kernel_launch(void* const* d_in, const int* in_sizes, int n_in,
                              void* d_out, int out_size, void* d_ws, size_t ws_size,
                              hipStream_t stream)
{
    (void)in_sizes; (void)n_in; (void)out_size; (void)ws_size;
    const float* hidden    = (const float*)d_in[0];
    const float* ln_t_g    = (const float*)d_in[1];
    const float* ln_t_b    = (const float*)d_in[2];
    const float* t_qkv_w   = (const float*)d_in[3];
    const float* t_qkv_b   = (const float*)d_in[4];
    const float* t_proj_w  = (const float*)d_in[5];
    const float* t_proj_b  = (const float*)d_in[6];
    const float* t_dense_w = (const float*)d_in[7];
    const float* t_dense_b = (const float*)d_in[8];
    const float* ln1_g     = (const float*)d_in[9];
    const float* ln1_b     = (const float*)d_in[10];
    const float* s_qkv_w   = (const float*)d_in[11];
    const float* s_qkv_b   = (const float*)d_in[12];
    const float* s_proj_w  = (const float*)d_in[13];
    const float* s_proj_b  = (const float*)d_in[14];
    const float* ln2_g     = (const float*)d_in[15];
    const float* ln2_b     = (const float*)d_in[16];
    const float* fc1_w     = (const float*)d_in[17];
    const float* fc1_b     = (const float*)d_in[18];
    const float* fc2_w     = (const float*)d_in[19];
    const float* fc2_b     = (const float*)d_in[20];

    char* ws = (char*)d_ws;
    size_t off = 0;
    auto alloc = [&](size_t bytes) -> char* {
        char* p = ws + off; off += (bytes + 255) & ~(size_t)255; return p;
    };
    bf16* wt_tqkv   = (bf16*)alloc((size_t)2304 * 768 * 2);
    bf16* wt_tdense = (bf16*)alloc((size_t)768 * 768 * 2);
    bf16* wt_sqkv   = (bf16*)alloc((size_t)2304 * 768 * 2);
    bf16* wt_sproj  = (bf16*)alloc((size_t)768 * 768 * 2);
    bf16* wt_fc1    = (bf16*)alloc((size_t)3072 * 768 * 2);
    bf16* wt_fc2    = (bf16*)alloc((size_t)768 * 3072 * 2);
    bf16* wcast     = (bf16*)alloc((size_t)768 * 768 * 2);
    bf16* wt_comb   = (bf16*)alloc((size_t)768 * 768 * 2);
    float* bc       = (float*)alloc((size_t)768 * 4);
    bf16* X         = (bf16*)alloc((size_t)R_S * CC * 2);
    char* qkv_base  = alloc((size_t)R_S * 2304 * 2);
    bf16* CTX       = (bf16*)alloc((size_t)R_S * CC * 2);
    bf16* P         = (bf16*)alloc((size_t)R_S * CC * 2);
    float* TEMB     = (float*)alloc((size_t)R_T * CC * 4);
    float* HS       = (float*)alloc((size_t)R_H * CC * 4);
    bf16* QKV = (bf16*)qkv_base;
    bf16* MID = (bf16*)qkv_base;   // MLP intermediate overlaps dead QKV+CTX region

    dim3 blk(256);
    dim3 blk512(512);

    // ---- weight prep ----
    k_transpose_all<<<9792, blk, 0, stream>>>(
        t_qkv_w, wt_tqkv, t_dense_w, wt_tdense, s_qkv_w, wt_sqkv,
        s_proj_w, wt_sproj, fc1_w, wt_fc1, fc2_w, wt_fc2, t_proj_w, wcast);
    k_bias_comb<<<768, blk, 0, stream>>>(t_proj_b, wt_tdense, t_dense_b, bc);
    k_gemm<<<6 * 6, blk512, 0, stream>>>(wt_tdense, wcast, nullptr, wt_comb, nullptr,
                                         768, 768, 768, 0, nullptr);

    // ---- temporal branch ----
    k_layernorm<<<R_T, blk, 0, stream>>>(nullptr, hidden, ln_t_g, ln_t_b, X, 0);
    k_gemm<<<98 * 18, blk512, 0, stream>>>(X, wt_tqkv, t_qkv_b, QKV, nullptr,
                                           R_T, 2304, 768, 0, nullptr);
    k_temporal_attn<<<1568, blk, 0, stream>>>(QKV, CTX);
    k_gemm<<<98 * 6, blk512, 0, stream>>>(CTX, wt_comb, bc, nullptr, TEMB,
                                          R_T, 768, 768, 1, hidden);

    // ---- spatial branch ----
    k_layernorm<<<R_S, blk, 0, stream>>>(TEMB, hidden, ln1_g, ln1_b, X, 1);
    k_gemm<<<99 * 18, blk512, 0, stream>>>(X, wt_sqkv, s_qkv_b, QKV, nullptr,
                                           R_S, 2304, 768, 0, nullptr);
    k_spatial_attn<<<dim3(12, 64), blk, 0, stream>>>(QKV, CTX);
    k_gemm<<<99 * 6, blk512, 0, stream>>>(CTX, wt_sproj, s_proj_b, P, nullptr,
                                          R_S, 768, 768, 0, nullptr);

    // ---- fused hs assembly + LN2 ----
    k_ln2_fused<<<R_H, blk, 0, stream>>>(hidden, TEMB, P, ln2_g, ln2_b, HS, X);

    // ---- MLP ----
    k_gemm<<<99 * 24, blk512, 0, stream>>>(X, wt_fc1, fc1_b, MID, nullptr,
                                           R_H, 3072, 768, 2, nullptr);
    k_gemm<<<99 * 6, blk512, 0, stream>>>(MID, wt_fc2, fc2_b, nullptr, (float*)d_out,
                                          R_H, 768, 3072, 3, HS);
}